// Round 1
// baseline (839.596 us; speedup 1.0000x reference)
//
#include <hip/hip_runtime.h>
#include <hip/hip_bf16.h>

namespace {
constexpr int kC = 256;
constexpr int kN = 2048;
constexpr int kB = 4;
constexpr int kHeads = 7;
constexpr int kW = 64;   // window width (head dim)
constexpr int kD = 32;   // window shift
constexpr int kOC = kHeads * kW; // 448
constexpr size_t kBCN = (size_t)kB * kC * kN;   // 2,097,152 floats
}

// ---------------- QKV projection + BN + ReLU ----------------
// out[b,o,n] = relu( (sum_c W[o,c] x[b,c,n]) * s[o] + bias[o] )
// 64x64 output tile per block; 16x16 threads, 4x4 regs each.
__global__ __launch_bounds__(256) void qkv_kernel(
    const float* __restrict__ x,
    const float* __restrict__ Wq, const float* __restrict__ sq, const float* __restrict__ bq,
    const float* __restrict__ Wk, const float* __restrict__ sk, const float* __restrict__ bk,
    const float* __restrict__ Wv, const float* __restrict__ sv, const float* __restrict__ bv,
    float* __restrict__ qo, float* __restrict__ ko, float* __restrict__ vo)
{
    const int nt  = blockIdx.x;          // n tile (0..31)
    const int ot  = blockIdx.y;          // o tile (0..3)
    const int b   = blockIdx.z / 3;
    const int mat = blockIdx.z % 3;
    const float* Wm  = (mat == 0) ? Wq : (mat == 1) ? Wk : Wv;
    const float* sm  = (mat == 0) ? sq : (mat == 1) ? sk : sv;
    const float* bm  = (mat == 0) ? bq : (mat == 1) ? bk : bv;
    float*       out = (mat == 0) ? qo : (mat == 1) ? ko : vo;

    __shared__ float Wt[64][68];  // [c][o], pitch 68 keeps rows 16B-aligned
    __shared__ float Xt[64][68];  // [c][n]

    const int tid = threadIdx.x;
    const int tm = tid & 15;      // n direction
    const int tn = tid >> 4;      // o direction
    const float* xb = x + (size_t)b * kC * kN;

    float acc[4][4] = {};

    for (int ct = 0; ct < kC; ct += 64) {
#pragma unroll
        for (int r = 0; r < 16; ++r) {
            int idx = r * 256 + tid;
            int oo = idx >> 6, cc = idx & 63;
            Wt[cc][oo] = Wm[(size_t)(ot * 64 + oo) * kC + ct + cc];
        }
#pragma unroll
        for (int r = 0; r < 16; ++r) {
            int idx = r * 256 + tid;
            int cc = idx >> 6, nn = idx & 63;
            Xt[cc][nn] = xb[(size_t)(ct + cc) * kN + nt * 64 + nn];
        }
        __syncthreads();
#pragma unroll 16
        for (int c = 0; c < 64; ++c) {
            float4 av  = *(const float4*)&Wt[c][tn * 4];
            float4 bv4 = *(const float4*)&Xt[c][tm * 4];
            float a[4]  = {av.x, av.y, av.z, av.w};
            float bb[4] = {bv4.x, bv4.y, bv4.z, bv4.w};
#pragma unroll
            for (int i = 0; i < 4; ++i)
#pragma unroll
                for (int j = 0; j < 4; ++j)
                    acc[i][j] = fmaf(a[i], bb[j], acc[i][j]);
        }
        __syncthreads();
    }
#pragma unroll
    for (int i = 0; i < 4; ++i) {
        int o = ot * 64 + tn * 4 + i;
        float sc = sm[o], bi = bm[o];
#pragma unroll
        for (int j = 0; j < 4; ++j) {
            int n = nt * 64 + tm * 4 + j;
            float v = fmaf(acc[i][j], sc, bi);
            out[((size_t)b * kC + o) * kN + n] = v > 0.f ? v : 0.f;
        }
    }
}

// ---------------- Flash-style windowed attention ----------------
// Per (b, h, 64-query tile): S[n,m] = sum_w Q[w,n] K[w,m] (no scale),
// online softmax over m, O[w,n] = sum_m P[n,m] V[w,m].
// Thread (tn,tm): n = n0+tn*4+i, m-cols tm*4+j for S; w = tm*4+j for O.
__global__ __launch_bounds__(256) void attn_kernel(
    const float* __restrict__ qb, const float* __restrict__ kb,
    const float* __restrict__ vb, float* __restrict__ ob)
{
    const int n0 = blockIdx.x * 64;
    const int h  = blockIdx.y;
    const int b  = blockIdx.z;
    const float* Q = qb + ((size_t)b * kC + h * kD) * kN;
    const float* K = kb + ((size_t)b * kC + h * kD) * kN;
    const float* V = vb + ((size_t)b * kC + h * kD) * kN;

    // 4 x 16KB = 64KB LDS total (fits static limit; 2 blocks/CU)
    __shared__ float Qt[64][64];  // [w][n]
    __shared__ float Kt[64][64];  // [w][m]
    __shared__ float Vt[64][64];  // [m][w], w-chunks XOR-swizzled by (m&15)
    __shared__ float Pt[64][64];  // [n][m]

    const int tid = threadIdx.x;
    const int tm = tid & 15;
    const int tn = tid >> 4;

#pragma unroll
    for (int r = 0; r < 16; ++r) {
        int idx = r * 256 + tid;
        int w = idx >> 6, n = idx & 63;
        Qt[w][n] = Q[(size_t)w * kN + n0 + n];
    }

    float mi[4], li[4], oacc[4][4];
#pragma unroll
    for (int i = 0; i < 4; ++i) {
        mi[i] = -1e30f; li[i] = 0.f;
#pragma unroll
        for (int j = 0; j < 4; ++j) oacc[i][j] = 0.f;
    }

    for (int m0 = 0; m0 < kN; m0 += 64) {
        __syncthreads();   // previous PV done before overwriting Kt/Vt
#pragma unroll
        for (int r = 0; r < 16; ++r) {
            int idx = r * 256 + tid;
            int w = idx >> 6, m = idx & 63;
            Kt[w][m] = K[(size_t)w * kN + m0 + m];
            Vt[m][(((w >> 2) ^ (m & 15)) << 2) | (w & 3)] = V[(size_t)w * kN + m0 + m];
        }
        __syncthreads();

        // S tile
        float s[4][4] = {};
#pragma unroll 16
        for (int w = 0; w < 64; ++w) {
            float4 av  = *(const float4*)&Qt[w][tn * 4];
            float4 bv4 = *(const float4*)&Kt[w][tm * 4];
            float a[4]  = {av.x, av.y, av.z, av.w};
            float bb[4] = {bv4.x, bv4.y, bv4.z, bv4.w};
#pragma unroll
            for (int i = 0; i < 4; ++i)
#pragma unroll
                for (int j = 0; j < 4; ++j)
                    s[i][j] = fmaf(a[i], bb[j], s[i][j]);
        }

        // online softmax; rows reduced across the 16 tm lanes (contiguous in wave)
#pragma unroll
        for (int i = 0; i < 4; ++i) {
            float rmax = fmaxf(fmaxf(s[i][0], s[i][1]), fmaxf(s[i][2], s[i][3]));
            rmax = fmaxf(rmax, __shfl_xor(rmax, 1, 16));
            rmax = fmaxf(rmax, __shfl_xor(rmax, 2, 16));
            rmax = fmaxf(rmax, __shfl_xor(rmax, 4, 16));
            rmax = fmaxf(rmax, __shfl_xor(rmax, 8, 16));
            float mnew  = fmaxf(mi[i], rmax);
            float alpha = __expf(mi[i] - mnew);
            mi[i] = mnew;
            float p0 = __expf(s[i][0] - mnew);
            float p1 = __expf(s[i][1] - mnew);
            float p2 = __expf(s[i][2] - mnew);
            float p3 = __expf(s[i][3] - mnew);
            float rs = p0 + p1 + p2 + p3;
            rs += __shfl_xor(rs, 1, 16);
            rs += __shfl_xor(rs, 2, 16);
            rs += __shfl_xor(rs, 4, 16);
            rs += __shfl_xor(rs, 8, 16);
            li[i] = li[i] * alpha + rs;
#pragma unroll
            for (int j = 0; j < 4; ++j) oacc[i][j] *= alpha;
            *(float4*)&Pt[tn * 4 + i][tm * 4] = make_float4(p0, p1, p2, p3);
        }
        __syncthreads();

        // O += P * V^T : oacc[i][j] (n=tn*4+i, w=tm*4+j)
#pragma unroll 4
        for (int m = 0; m < 64; m += 4) {
            float4 vv[4];
#pragma unroll
            for (int mm = 0; mm < 4; ++mm) {
                int row = m + mm;
                vv[mm] = *(const float4*)&Vt[row][(tm ^ (row & 15)) << 2];
            }
#pragma unroll
            for (int i = 0; i < 4; ++i) {
                float4 pp = *(const float4*)&Pt[tn * 4 + i][m];
                float pa[4] = {pp.x, pp.y, pp.z, pp.w};
#pragma unroll
                for (int mm = 0; mm < 4; ++mm) {
                    oacc[i][0] = fmaf(pa[mm], vv[mm].x, oacc[i][0]);
                    oacc[i][1] = fmaf(pa[mm], vv[mm].y, oacc[i][1]);
                    oacc[i][2] = fmaf(pa[mm], vv[mm].z, oacc[i][2]);
                    oacc[i][3] = fmaf(pa[mm], vv[mm].w, oacc[i][3]);
                }
            }
        }
    }

#pragma unroll
    for (int i = 0; i < 4; ++i) {
        float inv = 1.f / li[i];
        int n = n0 + tn * 4 + i;
#pragma unroll
        for (int j = 0; j < 4; ++j) {
            int w = tm * 4 + j;
            ob[((size_t)b * kOC + h * kW + w) * kN + n] = oacc[i][j] * inv;
        }
    }
}

// ---------------- Final projection + bias + BN + ReLU ----------------
// out[b,o,n] = relu( ((sum_c Wf[o,c] O[b,c,n]) + bf[o]) * sf[o] + bff[o] )
__global__ __launch_bounds__(256) void proj_kernel(
    const float* __restrict__ Ob, const float* __restrict__ Wf,
    const float* __restrict__ bf, const float* __restrict__ sf,
    const float* __restrict__ bff, float* __restrict__ out)
{
    const int nt = blockIdx.x;
    const int ot = blockIdx.y;
    const int b  = blockIdx.z;
    __shared__ float Wt[64][68];  // [c][o]
    __shared__ float Xt[64][68];  // [c][n]
    const int tid = threadIdx.x;
    const int tm = tid & 15;
    const int tn = tid >> 4;
    const float* xb = Ob + (size_t)b * kOC * kN;
    float acc[4][4] = {};

    for (int ct = 0; ct < kOC; ct += 64) {
#pragma unroll
        for (int r = 0; r < 16; ++r) {
            int idx = r * 256 + tid;
            int oo = idx >> 6, cc = idx & 63;
            Wt[cc][oo] = Wf[(size_t)(ot * 64 + oo) * kOC + ct + cc];
        }
#pragma unroll
        for (int r = 0; r < 16; ++r) {
            int idx = r * 256 + tid;
            int cc = idx >> 6, nn = idx & 63;
            Xt[cc][nn] = xb[(size_t)(ct + cc) * kN + nt * 64 + nn];
        }
        __syncthreads();
#pragma unroll 16
        for (int c = 0; c < 64; ++c) {
            float4 av  = *(const float4*)&Wt[c][tn * 4];
            float4 bv4 = *(const float4*)&Xt[c][tm * 4];
            float a[4]  = {av.x, av.y, av.z, av.w};
            float bb[4] = {bv4.x, bv4.y, bv4.z, bv4.w};
#pragma unroll
            for (int i = 0; i < 4; ++i)
#pragma unroll
                for (int j = 0; j < 4; ++j)
                    acc[i][j] = fmaf(a[i], bb[j], acc[i][j]);
        }
        __syncthreads();
    }
#pragma unroll
    for (int i = 0; i < 4; ++i) {
        int o = ot * 64 + tn * 4 + i;
        float bfv = bf[o], sfv = sf[o], bffv = bff[o];
#pragma unroll
        for (int j = 0; j < 4; ++j) {
            int n = nt * 64 + tm * 4 + j;
            float y = fmaf(acc[i][j] + bfv, sfv, bffv);
            out[((size_t)b * kC + o) * kN + n] = y > 0.f ? y : 0.f;
        }
    }
}

extern "C" void kernel_launch(void* const* d_in, const int* in_sizes, int n_in,
                              void* d_out, int out_size, void* d_ws, size_t ws_size,
                              hipStream_t stream) {
    const float* x   = (const float*)d_in[0];
    const float* Wq  = (const float*)d_in[1];
    const float* sq  = (const float*)d_in[2];
    const float* bq  = (const float*)d_in[3];
    const float* Wk  = (const float*)d_in[4];
    const float* sk  = (const float*)d_in[5];
    const float* bk  = (const float*)d_in[6];
    const float* Wv  = (const float*)d_in[7];
    const float* sv  = (const float*)d_in[8];
    const float* bv  = (const float*)d_in[9];
    const float* Wf  = (const float*)d_in[10];
    const float* bf  = (const float*)d_in[11];
    const float* sf  = (const float*)d_in[12];
    const float* bff = (const float*)d_in[13];
    float* out = (float*)d_out;

    float* ws = (float*)d_ws;
    float* qb = ws;               // B*C*N
    float* kb = qb + kBCN;
    float* vb = kb + kBCN;
    float* Ob = vb + kBCN;        // B*448*N

    qkv_kernel<<<dim3(kN / 64, kC / 64, kB * 3), 256, 0, stream>>>(
        x, Wq, sq, bq, Wk, sk, bk, Wv, sv, bv, qb, kb, vb);
    attn_kernel<<<dim3(kN / 64, kHeads, kB), 256, 0, stream>>>(qb, kb, vb, Ob);
    proj_kernel<<<dim3(kN / 64, kC / 64, kB), 256, 0, stream>>>(Ob, Wf, bf, sf, bff, out);
}

// Round 2
// 373.091 us; speedup vs baseline: 2.2504x; 2.2504x over previous
//
#include <hip/hip_runtime.h>
#include <hip/hip_bf16.h>

typedef __attribute__((ext_vector_type(8))) short bf16x8;
typedef __attribute__((ext_vector_type(4))) float f32x4;

namespace {
constexpr int kC = 256;
constexpr int kN = 2048;
constexpr int kB = 4;
constexpr int kHeads = 7;
constexpr int kOC = kHeads * 64; // 448
}

static __device__ __forceinline__ ushort f2bf(float f) {
    union { float f; unsigned u; } v; v.f = f;
    unsigned r = v.u + 0x7fffu + ((v.u >> 16) & 1u);
    return (ushort)(r >> 16);
}

// ---------------- QKV projection + BN + ReLU (fp32 compute, bf16 out) ------
// q,k written TRANSPOSED bf16: qT[(b*N + n)*C + c]; v natural: v[(b*C+c)*N + n]
__global__ __launch_bounds__(256) void qkv_kernel(
    const float* __restrict__ x,
    const float* __restrict__ Wq, const float* __restrict__ sq, const float* __restrict__ bq,
    const float* __restrict__ Wk, const float* __restrict__ sk, const float* __restrict__ bk,
    const float* __restrict__ Wv, const float* __restrict__ sv, const float* __restrict__ bv,
    ushort* __restrict__ qTo, ushort* __restrict__ kTo, ushort* __restrict__ vo)
{
    const int nt  = blockIdx.x;
    const int ot  = blockIdx.y;
    const int b   = blockIdx.z / 3;
    const int mat = blockIdx.z % 3;
    const float* Wm  = (mat == 0) ? Wq : (mat == 1) ? Wk : Wv;
    const float* sm  = (mat == 0) ? sq : (mat == 1) ? sk : sv;
    const float* bm  = (mat == 0) ? bq : (mat == 1) ? bk : bv;
    ushort*      out = (mat == 0) ? qTo : (mat == 1) ? kTo : vo;

    __shared__ float Wt[64][68];
    __shared__ float Xt[64][68];

    const int tid = threadIdx.x;
    const int tm = tid & 15;
    const int tn = tid >> 4;
    const float* xb = x + (size_t)b * kC * kN;

    float acc[4][4] = {};

    for (int ct = 0; ct < kC; ct += 64) {
#pragma unroll
        for (int r = 0; r < 16; ++r) {
            int idx = r * 256 + tid;
            int oo = idx >> 6, cc = idx & 63;
            Wt[cc][oo] = Wm[(size_t)(ot * 64 + oo) * kC + ct + cc];
        }
#pragma unroll
        for (int r = 0; r < 16; ++r) {
            int idx = r * 256 + tid;
            int cc = idx >> 6, nn = idx & 63;
            Xt[cc][nn] = xb[(size_t)(ct + cc) * kN + nt * 64 + nn];
        }
        __syncthreads();
#pragma unroll 16
        for (int c = 0; c < 64; ++c) {
            float4 av  = *(const float4*)&Wt[c][tn * 4];
            float4 bv4 = *(const float4*)&Xt[c][tm * 4];
            float a[4]  = {av.x, av.y, av.z, av.w};
            float bb[4] = {bv4.x, bv4.y, bv4.z, bv4.w};
#pragma unroll
            for (int i = 0; i < 4; ++i)
#pragma unroll
                for (int j = 0; j < 4; ++j)
                    acc[i][j] = fmaf(a[i], bb[j], acc[i][j]);
        }
        __syncthreads();
    }

    float r[4][4];
#pragma unroll
    for (int i = 0; i < 4; ++i) {
        int o = ot * 64 + tn * 4 + i;
        float sc = sm[o], bi = bm[o];
#pragma unroll
        for (int j = 0; j < 4; ++j) {
            float v = fmaf(acc[i][j], sc, bi);
            r[i][j] = v > 0.f ? v : 0.f;
        }
    }
    if (mat < 2) {
        // transposed store: [(b*N + n)*C + c], pack 4 consecutive c
#pragma unroll
        for (int j = 0; j < 4; ++j) {
            int n = nt * 64 + tm * 4 + j;
            ushort4 pk;
            pk.x = f2bf(r[0][j]); pk.y = f2bf(r[1][j]);
            pk.z = f2bf(r[2][j]); pk.w = f2bf(r[3][j]);
            *(ushort4*)&out[((size_t)b * kN + n) * kC + ot * 64 + tn * 4] = pk;
        }
    } else {
        // natural store: [(b*C + c)*N + n], pack 4 consecutive n
#pragma unroll
        for (int i = 0; i < 4; ++i) {
            int o = ot * 64 + tn * 4 + i;
            ushort4 pk;
            pk.x = f2bf(r[i][0]); pk.y = f2bf(r[i][1]);
            pk.z = f2bf(r[i][2]); pk.w = f2bf(r[i][3]);
            *(ushort4*)&out[((size_t)b * kC + o) * kN + nt * 64 + tm * 4] = pk;
        }
    }
}

// ---------------- MFMA flash attention (computes S^T = K^T Q) --------------
// Block: 128 threads = 2 waves; Q-tile 64 (32 n per wave); m-loop step 64.
// LDS sK[m][w], sV[w][m], sP[n][m] all 64x64 bf16, 16B-block XOR swizzled.
__global__ __launch_bounds__(128) void attn_kernel(
    const ushort* __restrict__ qT, const ushort* __restrict__ kT,
    const ushort* __restrict__ vb, float* __restrict__ ob)
{
    const int n0  = blockIdx.x * 64;
    const int h   = blockIdx.y;
    const int b   = blockIdx.z;
    const int tid = threadIdx.x;
    const int lane = tid & 63;
    const int wav  = tid >> 6;          // 0..1
    const int quad = lane >> 4;         // 0..3
    const int l16  = lane & 15;

    __shared__ __align__(16) ushort sK[64 * 64];
    __shared__ __align__(16) ushort sV[64 * 64];
    __shared__ __align__(16) ushort sP[64 * 64];

    const ushort* qTb = qT + (size_t)b * kN * kC;
    const ushort* kTb = kT + (size_t)b * kN * kC;
    const ushort* vbb = vb + ((size_t)b * kC + h * 32) * kN;

    // Q B-fragments: loop-invariant, kept in registers. [kstep][nt2]
    bf16x8 qf[2][2];
#pragma unroll
    for (int kk = 0; kk < 2; ++kk)
#pragma unroll
        for (int nt2 = 0; nt2 < 2; ++nt2) {
            int ng = n0 + wav * 32 + nt2 * 16 + l16;
            qf[kk][nt2] = *(const bf16x8*)(qTb + (size_t)ng * kC + h * 32 + kk * 32 + quad * 8);
        }

    f32x4 oacc[4][2];
#pragma unroll
    for (int wt = 0; wt < 4; ++wt)
#pragma unroll
        for (int nt2 = 0; nt2 < 2; ++nt2)
#pragma unroll
            for (int r4 = 0; r4 < 4; ++r4) oacc[wt][nt2][r4] = 0.f;
    float mi[2] = {-1e30f, -1e30f};
    float li[2] = {0.f, 0.f};

    for (int m0 = 0; m0 < kN; m0 += 64) {
        __syncthreads();   // previous iteration's K/V reads complete
        // stage K^T tile: rows m, 64 bf16 each (8 x 16B blocks, swizzled)
#pragma unroll
        for (int p = 0; p < 4; ++p) {
            int idx = p * 128 + tid;
            int row = idx >> 3, blk = idx & 7;
            int4 d = *(const int4*)(kTb + (size_t)(m0 + row) * kC + h * 32 + blk * 8);
            *(int4*)&sK[row * 64 + ((blk ^ (row & 7)) * 8)] = d;
        }
        // stage V tile: rows w (natural layout along m)
#pragma unroll
        for (int p = 0; p < 4; ++p) {
            int idx = p * 128 + tid;
            int w = idx >> 3, blk = idx & 7;
            int4 d = *(const int4*)(vbb + (size_t)w * kN + m0 + blk * 8);
            *(int4*)&sV[w * 64 + ((blk ^ (w & 7)) * 8)] = d;
        }
        __syncthreads();

        // S^T[m][n] = sum_w K^T[m][w] Q[w][n]
        f32x4 sacc[4][2];
#pragma unroll
        for (int mt = 0; mt < 4; ++mt)
#pragma unroll
            for (int nt2 = 0; nt2 < 2; ++nt2)
#pragma unroll
                for (int r4 = 0; r4 < 4; ++r4) sacc[mt][nt2][r4] = 0.f;
#pragma unroll
        for (int kk = 0; kk < 2; ++kk) {
#pragma unroll
            for (int mt = 0; mt < 4; ++mt) {
                int row = mt * 16 + l16;
                bf16x8 af = *(const bf16x8*)&sK[row * 64 + (((kk * 4 + quad) ^ (row & 7)) * 8)];
#pragma unroll
                for (int nt2 = 0; nt2 < 2; ++nt2)
                    sacc[mt][nt2] = __builtin_amdgcn_mfma_f32_16x16x32_bf16(
                        af, qf[kk][nt2], sacc[mt][nt2], 0, 0, 0);
            }
        }

        // online softmax (per n-column; lane's column is l16, replicated over quads)
#pragma unroll
        for (int nt2 = 0; nt2 < 2; ++nt2) {
            float mloc = -1e30f;
#pragma unroll
            for (int mt = 0; mt < 4; ++mt)
#pragma unroll
                for (int r4 = 0; r4 < 4; ++r4) mloc = fmaxf(mloc, sacc[mt][nt2][r4]);
            mloc = fmaxf(mloc, __shfl_xor(mloc, 16));
            mloc = fmaxf(mloc, __shfl_xor(mloc, 32));
            float mnew = fmaxf(mi[nt2], mloc);
            float al = __expf(mi[nt2] - mnew);
            mi[nt2] = mnew;
            float sum = 0.f;
            int nrow = wav * 32 + nt2 * 16 + l16;
#pragma unroll
            for (int mt = 0; mt < 4; ++mt) {
                float p0 = __expf(sacc[mt][nt2][0] - mnew);
                float p1 = __expf(sacc[mt][nt2][1] - mnew);
                float p2 = __expf(sacc[mt][nt2][2] - mnew);
                float p3 = __expf(sacc[mt][nt2][3] - mnew);
                sum += (p0 + p1) + (p2 + p3);
                ushort4 pk; pk.x = f2bf(p0); pk.y = f2bf(p1); pk.z = f2bf(p2); pk.w = f2bf(p3);
                int bidx = (mt * 2 + (quad >> 1)) ^ (nrow & 7);
                *(ushort4*)&sP[nrow * 64 + bidx * 8 + (quad & 1) * 4] = pk;
            }
            sum += __shfl_xor(sum, 16);
            sum += __shfl_xor(sum, 32);
            li[nt2] = li[nt2] * al + sum;
#pragma unroll
            for (int wt = 0; wt < 4; ++wt)
#pragma unroll
                for (int r4 = 0; r4 < 4; ++r4) oacc[wt][nt2][r4] *= al;
        }

        // O[w][n] += sum_m V[w][m] P[m][n]   (P read from own wave's rows only)
#pragma unroll
        for (int ks = 0; ks < 2; ++ks) {
            bf16x8 pf[2];
#pragma unroll
            for (int nt2 = 0; nt2 < 2; ++nt2) {
                int nr = wav * 32 + nt2 * 16 + l16;
                pf[nt2] = *(const bf16x8*)&sP[nr * 64 + (((ks * 4 + quad) ^ (nr & 7)) * 8)];
            }
#pragma unroll
            for (int wt = 0; wt < 4; ++wt) {
                int wr = wt * 16 + l16;
                bf16x8 vf = *(const bf16x8*)&sV[wr * 64 + (((ks * 4 + quad) ^ (wr & 7)) * 8)];
#pragma unroll
                for (int nt2 = 0; nt2 < 2; ++nt2)
                    oacc[wt][nt2] = __builtin_amdgcn_mfma_f32_16x16x32_bf16(
                        vf, pf[nt2], oacc[wt][nt2], 0, 0, 0);
            }
        }
    }

    // epilogue: normalize and store fp32 O[b][h*64+w][n]
#pragma unroll
    for (int nt2 = 0; nt2 < 2; ++nt2) {
        float inv = 1.f / li[nt2];
        int n = n0 + wav * 32 + nt2 * 16 + l16;
#pragma unroll
        for (int wt = 0; wt < 4; ++wt)
#pragma unroll
            for (int r4 = 0; r4 < 4; ++r4) {
                int w = wt * 16 + quad * 4 + r4;
                ob[((size_t)b * kOC + h * 64 + w) * kN + n] = oacc[wt][nt2][r4] * inv;
            }
    }
}

// ---------------- Final projection + bias + BN + ReLU (fp32) ---------------
__global__ __launch_bounds__(256) void proj_kernel(
    const float* __restrict__ Ob, const float* __restrict__ Wf,
    const float* __restrict__ bf, const float* __restrict__ sf,
    const float* __restrict__ bff, float* __restrict__ out)
{
    const int nt = blockIdx.x;
    const int ot = blockIdx.y;
    const int b  = blockIdx.z;
    __shared__ float Wt[64][68];
    __shared__ float Xt[64][68];
    const int tid = threadIdx.x;
    const int tm = tid & 15;
    const int tn = tid >> 4;
    const float* xb = Ob + (size_t)b * kOC * kN;
    float acc[4][4] = {};

    for (int ct = 0; ct < kOC; ct += 64) {
#pragma unroll
        for (int r = 0; r < 16; ++r) {
            int idx = r * 256 + tid;
            int oo = idx >> 6, cc = idx & 63;
            Wt[cc][oo] = Wf[(size_t)(ot * 64 + oo) * kOC + ct + cc];
        }
#pragma unroll
        for (int r = 0; r < 16; ++r) {
            int idx = r * 256 + tid;
            int cc = idx >> 6, nn = idx & 63;
            Xt[cc][nn] = xb[(size_t)(ct + cc) * kN + nt * 64 + nn];
        }
        __syncthreads();
#pragma unroll 16
        for (int c = 0; c < 64; ++c) {
            float4 av  = *(const float4*)&Wt[c][tn * 4];
            float4 bv4 = *(const float4*)&Xt[c][tm * 4];
            float a[4]  = {av.x, av.y, av.z, av.w};
            float bb[4] = {bv4.x, bv4.y, bv4.z, bv4.w};
#pragma unroll
            for (int i = 0; i < 4; ++i)
#pragma unroll
                for (int j = 0; j < 4; ++j)
                    acc[i][j] = fmaf(a[i], bb[j], acc[i][j]);
        }
        __syncthreads();
    }
#pragma unroll
    for (int i = 0; i < 4; ++i) {
        int o = ot * 64 + tn * 4 + i;
        float bfv = bf[o], sfv = sf[o], bffv = bff[o];
#pragma unroll
        for (int j = 0; j < 4; ++j) {
            int n = nt * 64 + tm * 4 + j;
            float y = fmaf(acc[i][j] + bfv, sfv, bffv);
            out[((size_t)b * kC + o) * kN + n] = y > 0.f ? y : 0.f;
        }
    }
}

extern "C" void kernel_launch(void* const* d_in, const int* in_sizes, int n_in,
                              void* d_out, int out_size, void* d_ws, size_t ws_size,
                              hipStream_t stream) {
    const float* x   = (const float*)d_in[0];
    const float* Wq  = (const float*)d_in[1];
    const float* sq  = (const float*)d_in[2];
    const float* bq  = (const float*)d_in[3];
    const float* Wk  = (const float*)d_in[4];
    const float* sk  = (const float*)d_in[5];
    const float* bk  = (const float*)d_in[6];
    const float* Wv  = (const float*)d_in[7];
    const float* sv  = (const float*)d_in[8];
    const float* bv  = (const float*)d_in[9];
    const float* Wf  = (const float*)d_in[10];
    const float* bf  = (const float*)d_in[11];
    const float* sf  = (const float*)d_in[12];
    const float* bff = (const float*)d_in[13];
    float* out = (float*)d_out;

    char* ws = (char*)d_ws;
    const size_t bcn = (size_t)kB * kN * kC;            // element count
    ushort* qT = (ushort*)ws;                           // 4 MB
    ushort* kT = (ushort*)(ws + bcn * 2);               // 4 MB
    ushort* vB = (ushort*)(ws + bcn * 4);               // 4 MB
    float*  Ob = (float*)(ws + bcn * 6);                // B*448*N fp32 = 14 MB

    qkv_kernel<<<dim3(kN / 64, kC / 64, kB * 3), 256, 0, stream>>>(
        x, Wq, sq, bq, Wk, sk, bk, Wv, sv, bv, qT, kT, vB);
    attn_kernel<<<dim3(kN / 64, kHeads, kB), 128, 0, stream>>>(qT, kT, vB, Ob);
    proj_kernel<<<dim3(kN / 64, kC / 64, kB), 256, 0, stream>>>(Ob, Wf, bf, sf, bff, out);
}

// Round 3
// 318.726 us; speedup vs baseline: 2.6342x; 1.1706x over previous
//
#include <hip/hip_runtime.h>
#include <hip/hip_bf16.h>

typedef __attribute__((ext_vector_type(8))) short bf16x8;
typedef __attribute__((ext_vector_type(4))) float f32x4;

namespace {
constexpr int kC = 256;
constexpr int kN = 2048;
constexpr int kB = 4;
constexpr int kHeads = 7;
constexpr int kOC = kHeads * 64;     // 448
constexpr int kSplit = 2;
constexpr int kMChunk = kN / kSplit; // 1024
}

static __device__ __forceinline__ ushort f2bf(float f) {
    union { float f; unsigned u; } v; v.f = f;
    unsigned r = v.u + 0x7fffu + ((v.u >> 16) & 1u);
    return (ushort)(r >> 16);
}
static __device__ __forceinline__ float bf2f(ushort u) {
    union { unsigned u; float f; } v; v.u = ((unsigned)u) << 16;
    return v.f;
}
// pack two floats to bf16 (RNE) in one dword: low = a, high = b
static __device__ __forceinline__ unsigned pack2bf(float a, float b) {
    union { float f; unsigned u; } x, y; x.f = a; y.f = b;
    unsigned ra = x.u + 0x7fffu + ((x.u >> 16) & 1u);
    unsigned rb = y.u + 0x7fffu + ((y.u >> 16) & 1u);
    return __builtin_amdgcn_perm(rb, ra, 0x07060302u); // [rb.hi16 : ra.hi16]
}

// ---------------- weight cast fp32 -> bf16 ----------------
__global__ __launch_bounds__(256) void cast_w_kernel(
    const float* __restrict__ Wq, const float* __restrict__ Wk,
    const float* __restrict__ Wv, const float* __restrict__ Wf,
    ushort* __restrict__ wq, ushort* __restrict__ wk,
    ushort* __restrict__ wv, ushort* __restrict__ wf)
{
    int which = blockIdx.y;
    const float* src = which == 0 ? Wq : which == 1 ? Wk : which == 2 ? Wv : Wf;
    ushort* dst      = which == 0 ? wq : which == 1 ? wk : which == 2 ? wv : wf;
    int n = (which == 3) ? kC * kOC : kC * kC;
    int i = (blockIdx.x * 256 + threadIdx.x) * 4;
    if (i < n) {
        float4 v = *(const float4*)(src + i);
        ushort4 p; p.x = f2bf(v.x); p.y = f2bf(v.y); p.z = f2bf(v.z); p.w = f2bf(v.w);
        *(ushort4*)(dst + i) = p;
    }
}

// ---------------- x transpose+cast: x[b][c][n] fp32 -> xT[b][n][c] bf16 -----
__global__ __launch_bounds__(256) void transpose_kernel(
    const float* __restrict__ x, ushort* __restrict__ xT)
{
    const int nt = blockIdx.x, ct = blockIdx.y, b = blockIdx.z;
    __shared__ float T[64][65];
    const int tid = threadIdx.x;
    const float* xb = x + ((size_t)b * kC + ct * 64) * kN + nt * 64;
#pragma unroll
    for (int p = 0; p < 16; ++p) {
        int idx = p * 256 + tid;
        int cc = idx >> 6, nn = idx & 63;
        T[cc][nn] = xb[(size_t)cc * kN + nn];
    }
    __syncthreads();
    ushort* xTb = xT + ((size_t)b * kN + nt * 64) * kC + ct * 64;
#pragma unroll
    for (int p = 0; p < 4; ++p) {
        int nn = p * 16 + (tid >> 4);
        int c4 = (tid & 15) * 4;
        ushort4 pk;
        pk.x = f2bf(T[c4 + 0][nn]); pk.y = f2bf(T[c4 + 1][nn]);
        pk.z = f2bf(T[c4 + 2][nn]); pk.w = f2bf(T[c4 + 3][nn]);
        *(ushort4*)&xTb[(size_t)nn * kC + c4] = pk;
    }
}

// ---------------- QKV projection, bf16 MFMA --------------------------------
// mat<2 (q,k): D[n][o] = sum_c xT[n][c] W[o][c] -> store transposed qT/kT[n][o]
// mat==2 (v):  D[o][n] = sum_c W[o][c] xT[n][c] -> store natural  v[o][n]
// block 128 thr (2 waves), output tile 64(rows) x 64(cols), wave = cols half.
__global__ __launch_bounds__(128) void qkv_kernel(
    const ushort* __restrict__ xT,
    const ushort* __restrict__ Wqb, const ushort* __restrict__ Wkb, const ushort* __restrict__ Wvb,
    const float* __restrict__ sq, const float* __restrict__ bq,
    const float* __restrict__ sk, const float* __restrict__ bk,
    const float* __restrict__ sv, const float* __restrict__ bv,
    ushort* __restrict__ qT, ushort* __restrict__ kT, ushort* __restrict__ vB)
{
    const int nt  = blockIdx.x;
    const int ot  = blockIdx.y;
    const int b   = blockIdx.z / 3;
    const int mat = blockIdx.z % 3;
    const ushort* Wb = mat == 0 ? Wqb : mat == 1 ? Wkb : Wvb;
    const float* sm = mat == 0 ? sq : mat == 1 ? sk : sv;
    const float* bm = mat == 0 ? bq : mat == 1 ? bk : bv;

    __shared__ __align__(16) ushort sW[64 * 64];
    __shared__ __align__(16) ushort sX[64 * 64];

    const int tid = threadIdx.x;
    const int lane = tid & 63, wav = tid >> 6;
    const int quad = lane >> 4, l16 = lane & 15;

    const ushort* xTb = xT + ((size_t)b * kN + nt * 64) * kC;
    const ushort* Wt  = Wb + (size_t)(ot * 64) * kC;

    f32x4 acc[4][2];
#pragma unroll
    for (int mt = 0; mt < 4; ++mt)
#pragma unroll
        for (int ntt = 0; ntt < 2; ++ntt)
#pragma unroll
            for (int r = 0; r < 4; ++r) acc[mt][ntt][r] = 0.f;

    for (int k0 = 0; k0 < kC; k0 += 64) {
        __syncthreads();
#pragma unroll
        for (int p = 0; p < 4; ++p) {
            int idx = p * 128 + tid;
            int row = idx >> 3, blk = idx & 7;
            *(int4*)&sW[row * 64 + ((blk ^ (row & 7)) * 8)] =
                *(const int4*)(Wt + (size_t)row * kC + k0 + blk * 8);
            *(int4*)&sX[row * 64 + ((blk ^ (row & 7)) * 8)] =
                *(const int4*)(xTb + (size_t)row * kC + k0 + blk * 8);
        }
        __syncthreads();
        const ushort* rowB = (mat < 2) ? sX : sW;  // A operand (rows)
        const ushort* colB = (mat < 2) ? sW : sX;  // B operand (cols)
#pragma unroll
        for (int ks = 0; ks < 2; ++ks) {
            bf16x8 bfr[2];
#pragma unroll
            for (int ntt = 0; ntt < 2; ++ntt) {
                int row = wav * 32 + ntt * 16 + l16;
                bfr[ntt] = *(const bf16x8*)&colB[row * 64 + (((ks * 4 + quad) ^ (row & 7)) * 8)];
            }
#pragma unroll
            for (int mt = 0; mt < 4; ++mt) {
                int row = mt * 16 + l16;
                bf16x8 af = *(const bf16x8*)&rowB[row * 64 + (((ks * 4 + quad) ^ (row & 7)) * 8)];
#pragma unroll
                for (int ntt = 0; ntt < 2; ++ntt)
                    acc[mt][ntt] = __builtin_amdgcn_mfma_f32_16x16x32_bf16(
                        af, bfr[ntt], acc[mt][ntt], 0, 0, 0);
            }
        }
    }

    if (mat < 2) {
        ushort* out = (mat == 0) ? qT : kT;
#pragma unroll
        for (int ntt = 0; ntt < 2; ++ntt) {
            int o = ot * 64 + wav * 32 + ntt * 16 + l16;
            float sc = sm[o], bi = bm[o];
#pragma unroll
            for (int mt = 0; mt < 4; ++mt)
#pragma unroll
                for (int r = 0; r < 4; ++r) {
                    int n = nt * 64 + mt * 16 + quad * 4 + r;
                    float v = fmaf(acc[mt][ntt][r], sc, bi);
                    out[((size_t)b * kN + n) * kC + o] = f2bf(v > 0.f ? v : 0.f);
                }
        }
    } else {
#pragma unroll
        for (int mt = 0; mt < 4; ++mt)
#pragma unroll
            for (int r = 0; r < 4; ++r) {
                int o = ot * 64 + mt * 16 + quad * 4 + r;
                float sc = sm[o], bi = bm[o];
#pragma unroll
                for (int ntt = 0; ntt < 2; ++ntt) {
                    int n = nt * 64 + wav * 32 + ntt * 16 + l16;
                    float v = fmaf(acc[mt][ntt][r], sc, bi);
                    vB[((size_t)b * kC + o) * kN + n] = f2bf(v > 0.f ? v : 0.f);
                }
            }
    }
}

// ---------------- MFMA flash attention, split-K over m ---------------------
// grid (32 ntiles, 7 heads, kB*kSplit); block 128 thr (2 waves).
// LDS: sKP (K tile, aliased by P after S-MFMA) + sV = 16 KB.
// K/V tiles prefetched to regs one iteration ahead.
__global__ __launch_bounds__(128) void attn_kernel(
    const ushort* __restrict__ qT, const ushort* __restrict__ kT,
    const ushort* __restrict__ vB,
    ushort* __restrict__ Opart, float* __restrict__ Ms, float* __restrict__ Ls)
{
    const int n0 = blockIdx.x * 64;
    const int h  = blockIdx.y;
    const int s  = blockIdx.z & 1;
    const int b  = blockIdx.z >> 1;
    const int tid = threadIdx.x;
    const int lane = tid & 63, wav = tid >> 6;
    const int quad = lane >> 4, l16 = lane & 15;

    __shared__ __align__(16) ushort sKP[64 * 64]; // K tile, then P tile
    __shared__ __align__(16) ushort sV[64 * 64];

    const ushort* qTb = qT + (size_t)b * kN * kC;
    const ushort* kTb = kT + (size_t)b * kN * kC;
    const ushort* vbb = vB + ((size_t)b * kC + h * 32) * kN;

    bf16x8 qf[2][2];
#pragma unroll
    for (int kk = 0; kk < 2; ++kk)
#pragma unroll
        for (int nt2 = 0; nt2 < 2; ++nt2) {
            int ng = n0 + wav * 32 + nt2 * 16 + l16;
            qf[kk][nt2] = *(const bf16x8*)(qTb + (size_t)ng * kC + h * 32 + kk * 32 + quad * 8);
        }

    f32x4 oacc[4][2];
#pragma unroll
    for (int wt = 0; wt < 4; ++wt)
#pragma unroll
        for (int nt2 = 0; nt2 < 2; ++nt2)
#pragma unroll
            for (int r = 0; r < 4; ++r) oacc[wt][nt2][r] = 0.f;
    float mi[2] = {-1e30f, -1e30f};
    float li[2] = {0.f, 0.f};

    const int mstart = s * kMChunk;
    int4 kreg[4], vreg[4];
#pragma unroll
    for (int p = 0; p < 4; ++p) {
        int idx = p * 128 + tid, row = idx >> 3, blk = idx & 7;
        kreg[p] = *(const int4*)(kTb + (size_t)(mstart + row) * kC + h * 32 + blk * 8);
        vreg[p] = *(const int4*)(vbb + (size_t)row * kN + mstart + blk * 8);
    }

    for (int it = 0; it < kMChunk / 64; ++it) {
        __syncthreads();  // prev iter's PV reads of sKP(P)/sV are done
#pragma unroll
        for (int p = 0; p < 4; ++p) {
            int idx = p * 128 + tid, row = idx >> 3, blk = idx & 7;
            *(int4*)&sKP[row * 64 + ((blk ^ (row & 7)) * 8)] = kreg[p];
            *(int4*)&sV [row * 64 + ((blk ^ (row & 7)) * 8)] = vreg[p];
        }
        if (it + 1 < kMChunk / 64) {
            int m1 = mstart + (it + 1) * 64;
#pragma unroll
            for (int p = 0; p < 4; ++p) {
                int idx = p * 128 + tid, row = idx >> 3, blk = idx & 7;
                kreg[p] = *(const int4*)(kTb + (size_t)(m1 + row) * kC + h * 32 + blk * 8);
                vreg[p] = *(const int4*)(vbb + (size_t)row * kN + m1 + blk * 8);
            }
        }
        __syncthreads();

        // S^T[m][n] = sum_w K[w][m] Q[w][n]
        f32x4 sacc[4][2];
#pragma unroll
        for (int mt = 0; mt < 4; ++mt)
#pragma unroll
            for (int nt2 = 0; nt2 < 2; ++nt2)
#pragma unroll
                for (int r = 0; r < 4; ++r) sacc[mt][nt2][r] = 0.f;
#pragma unroll
        for (int kk = 0; kk < 2; ++kk)
#pragma unroll
            for (int mt = 0; mt < 4; ++mt) {
                int row = mt * 16 + l16;
                bf16x8 af = *(const bf16x8*)&sKP[row * 64 + (((kk * 4 + quad) ^ (row & 7)) * 8)];
#pragma unroll
                for (int nt2 = 0; nt2 < 2; ++nt2)
                    sacc[mt][nt2] = __builtin_amdgcn_mfma_f32_16x16x32_bf16(
                        af, qf[kk][nt2], sacc[mt][nt2], 0, 0, 0);
            }
        __syncthreads();  // all waves done reading K before P overwrites sKP

        // online softmax (column n = l16 within each 16-tile; reduce over quads)
#pragma unroll
        for (int nt2 = 0; nt2 < 2; ++nt2) {
            float mloc = -1e30f;
#pragma unroll
            for (int mt = 0; mt < 4; ++mt)
#pragma unroll
                for (int r = 0; r < 4; ++r) mloc = fmaxf(mloc, sacc[mt][nt2][r]);
            mloc = fmaxf(mloc, __shfl_xor(mloc, 16));
            mloc = fmaxf(mloc, __shfl_xor(mloc, 32));
            float mnew = fmaxf(mi[nt2], mloc);
            float al = __expf(mi[nt2] - mnew);
            mi[nt2] = mnew;
            int nrow = wav * 32 + nt2 * 16 + l16;
            float sum = 0.f;
#pragma unroll
            for (int mt = 0; mt < 4; ++mt) {
                float p0 = __expf(sacc[mt][nt2][0] - mnew);
                float p1 = __expf(sacc[mt][nt2][1] - mnew);
                float p2 = __expf(sacc[mt][nt2][2] - mnew);
                float p3 = __expf(sacc[mt][nt2][3] - mnew);
                sum += (p0 + p1) + (p2 + p3);
                int bidx = (mt * 2 + (quad >> 1)) ^ (nrow & 7);
                uint2 pk; pk.x = pack2bf(p0, p1); pk.y = pack2bf(p2, p3);
                *(uint2*)&sKP[nrow * 64 + bidx * 8 + (quad & 1) * 4] = pk;
            }
            sum += __shfl_xor(sum, 16);
            sum += __shfl_xor(sum, 32);
            li[nt2] = li[nt2] * al + sum;
#pragma unroll
            for (int wt = 0; wt < 4; ++wt)
#pragma unroll
                for (int r = 0; r < 4; ++r) oacc[wt][nt2][r] *= al;
        }

        // O[w][n] += sum_m V[w][m] P[m][n]; pf reads only own wave's rows
#pragma unroll
        for (int ks = 0; ks < 2; ++ks) {
            bf16x8 pf[2];
#pragma unroll
            for (int nt2 = 0; nt2 < 2; ++nt2) {
                int nr = wav * 32 + nt2 * 16 + l16;
                pf[nt2] = *(const bf16x8*)&sKP[nr * 64 + (((ks * 4 + quad) ^ (nr & 7)) * 8)];
            }
#pragma unroll
            for (int wt = 0; wt < 4; ++wt) {
                int wr = wt * 16 + l16;
                bf16x8 vf = *(const bf16x8*)&sV[wr * 64 + (((ks * 4 + quad) ^ (wr & 7)) * 8)];
#pragma unroll
                for (int nt2 = 0; nt2 < 2; ++nt2)
                    oacc[wt][nt2] = __builtin_amdgcn_mfma_f32_16x16x32_bf16(
                        vf, pf[nt2], oacc[wt][nt2], 0, 0, 0);
            }
        }
    }

    // epilogue: per-split normalized O (bf16) + (m,l) stats
#pragma unroll
    for (int nt2 = 0; nt2 < 2; ++nt2) {
        float inv = 1.f / li[nt2];
        int n = n0 + wav * 32 + nt2 * 16 + l16;
        size_t bn = (size_t)b * kN + n;
#pragma unroll
        for (int wt = 0; wt < 4; ++wt) {
            ushort4 pk;
            pk.x = f2bf(oacc[wt][nt2][0] * inv);
            pk.y = f2bf(oacc[wt][nt2][1] * inv);
            pk.z = f2bf(oacc[wt][nt2][2] * inv);
            pk.w = f2bf(oacc[wt][nt2][3] * inv);
            *(ushort4*)&Opart[((size_t)s * kB * kN + bn) * kOC + h * 64 + wt * 16 + quad * 4] = pk;
        }
        if (quad == 0) {
            size_t si = ((size_t)(s * kB + b) * kHeads + h) * kN + n;
            Ms[si] = mi[nt2];
            Ls[si] = li[nt2];
        }
    }
}

// ---------------- combine splits -> OT[b][n][c] bf16 -----------------------
__global__ __launch_bounds__(256) void combine_kernel(
    const ushort* __restrict__ Opart, const float* __restrict__ Ms,
    const float* __restrict__ Ls, ushort* __restrict__ OT)
{
    int t = blockIdx.x * 256 + threadIdx.x;   // 0 .. kB*kN*112-1
    int bn = t / 112;
    int c4 = (t % 112) * 4;
    int h  = c4 >> 6;
    int b = bn >> 11, n = bn & 2047;
    size_t si = ((size_t)b * kHeads + h) * kN + n;
    size_t soff = (size_t)kB * kHeads * kN;
    float m1 = Ms[si], m2 = Ms[si + soff];
    float l1 = Ls[si], l2 = Ls[si + soff];
    float M = fmaxf(m1, m2);
    float g1 = l1 * __expf(m1 - M), g2 = l2 * __expf(m2 - M);
    float inv = 1.f / (g1 + g2);
    float w1 = g1 * inv, w2 = g2 * inv;
    size_t o1 = (size_t)bn * kOC + c4;
    size_t o2 = o1 + (size_t)kB * kN * kOC;
    ushort4 a = *(const ushort4*)&Opart[o1];
    ushort4 c = *(const ushort4*)&Opart[o2];
    ushort4 pk;
    pk.x = f2bf(bf2f(a.x) * w1 + bf2f(c.x) * w2);
    pk.y = f2bf(bf2f(a.y) * w1 + bf2f(c.y) * w2);
    pk.z = f2bf(bf2f(a.z) * w1 + bf2f(c.z) * w2);
    pk.w = f2bf(bf2f(a.w) * w1 + bf2f(c.w) * w2);
    *(ushort4*)&OT[(size_t)bn * kOC + c4] = pk;
}

// ---------------- final projection, bf16 MFMA ------------------------------
// D[o][n] = sum_c Wf[o][c] OT[n][c]; out = relu((D + bf)*sf + bff), fp32
__global__ __launch_bounds__(128) void proj_kernel(
    const ushort* __restrict__ OT, const ushort* __restrict__ Wfb,
    const float* __restrict__ bf_, const float* __restrict__ sf,
    const float* __restrict__ bff, float* __restrict__ out)
{
    const int nt = blockIdx.x;
    const int ot = blockIdx.y;
    const int b  = blockIdx.z;
    __shared__ __align__(16) ushort sA[64 * 64];
    __shared__ __align__(16) ushort sB[64 * 64];
    const int tid = threadIdx.x;
    const int lane = tid & 63, wav = tid >> 6;
    const int quad = lane >> 4, l16 = lane & 15;

    const ushort* Wt = Wfb + (size_t)(ot * 64) * kOC;
    const ushort* Ob = OT + ((size_t)b * kN + nt * 64) * kOC;

    f32x4 acc[4][2];
#pragma unroll
    for (int mt = 0; mt < 4; ++mt)
#pragma unroll
        for (int ntt = 0; ntt < 2; ++ntt)
#pragma unroll
            for (int r = 0; r < 4; ++r) acc[mt][ntt][r] = 0.f;

    for (int k0 = 0; k0 < kOC; k0 += 64) {
        __syncthreads();
#pragma unroll
        for (int p = 0; p < 4; ++p) {
            int idx = p * 128 + tid;
            int row = idx >> 3, blk = idx & 7;
            *(int4*)&sA[row * 64 + ((blk ^ (row & 7)) * 8)] =
                *(const int4*)(Wt + (size_t)row * kOC + k0 + blk * 8);
            *(int4*)&sB[row * 64 + ((blk ^ (row & 7)) * 8)] =
                *(const int4*)(Ob + (size_t)row * kOC + k0 + blk * 8);
        }
        __syncthreads();
#pragma unroll
        for (int ks = 0; ks < 2; ++ks) {
            bf16x8 bfr[2];
#pragma unroll
            for (int ntt = 0; ntt < 2; ++ntt) {
                int row = wav * 32 + ntt * 16 + l16;
                bfr[ntt] = *(const bf16x8*)&sB[row * 64 + (((ks * 4 + quad) ^ (row & 7)) * 8)];
            }
#pragma unroll
            for (int mt = 0; mt < 4; ++mt) {
                int row = mt * 16 + l16;
                bf16x8 af = *(const bf16x8*)&sA[row * 64 + (((ks * 4 + quad) ^ (row & 7)) * 8)];
#pragma unroll
                for (int ntt = 0; ntt < 2; ++ntt)
                    acc[mt][ntt] = __builtin_amdgcn_mfma_f32_16x16x32_bf16(
                        af, bfr[ntt], acc[mt][ntt], 0, 0, 0);
            }
        }
    }
#pragma unroll
    for (int mt = 0; mt < 4; ++mt)
#pragma unroll
        for (int r = 0; r < 4; ++r) {
            int o = ot * 64 + mt * 16 + quad * 4 + r;
            float bfv = bf_[o], sfv = sf[o], bffv = bff[o];
#pragma unroll
            for (int ntt = 0; ntt < 2; ++ntt) {
                int n = nt * 64 + wav * 32 + ntt * 16 + l16;
                float y = fmaf(acc[mt][ntt][r] + bfv, sfv, bffv);
                out[((size_t)b * kC + o) * kN + n] = y > 0.f ? y : 0.f;
            }
        }
}

extern "C" void kernel_launch(void* const* d_in, const int* in_sizes, int n_in,
                              void* d_out, int out_size, void* d_ws, size_t ws_size,
                              hipStream_t stream) {
    const float* x   = (const float*)d_in[0];
    const float* Wq  = (const float*)d_in[1];
    const float* sq  = (const float*)d_in[2];
    const float* bq  = (const float*)d_in[3];
    const float* Wk  = (const float*)d_in[4];
    const float* sk  = (const float*)d_in[5];
    const float* bk  = (const float*)d_in[6];
    const float* Wv  = (const float*)d_in[7];
    const float* sv  = (const float*)d_in[8];
    const float* bv  = (const float*)d_in[9];
    const float* Wf  = (const float*)d_in[10];
    const float* bf_ = (const float*)d_in[11];
    const float* sf  = (const float*)d_in[12];
    const float* bff = (const float*)d_in[13];
    float* out = (float*)d_out;

    // workspace layout (bytes), total ~33 MB
    char* ws = (char*)d_ws;
    ushort* xT  = (ushort*)(ws);                         // 4*2048*256*2 = 4,194,304
    ushort* Wqb = (ushort*)(ws + 4194304);               // 131,072
    ushort* Wkb = (ushort*)(ws + 4325376);               // 131,072
    ushort* Wvb = (ushort*)(ws + 4456448);               // 131,072
    ushort* Wfb = (ushort*)(ws + 4587520);               // 229,376
    ushort* qT  = (ushort*)(ws + 4816896);               // 4,194,304
    ushort* kT  = (ushort*)(ws + 9011200);               // 4,194,304
    ushort* vB  = (ushort*)(ws + 13205504);              // 4,194,304
    ushort* Opart = (ushort*)(ws + 17399808);            // 2*4*2048*448*2 = 14,680,064
    float*  Ms  = (float*)(ws + 32079872);               // 458,752
    float*  Ls  = (float*)(ws + 32538624);               // 458,752
    ushort* OT  = qT;  // alias: qT/kT dead after attn; OT (7.34 MB) fits in qT+kT

    cast_w_kernel<<<dim3(112, 4), 256, 0, stream>>>(Wq, Wk, Wv, Wf, Wqb, Wkb, Wvb, Wfb);
    transpose_kernel<<<dim3(kN / 64, kC / 64, kB), 256, 0, stream>>>(x, xT);
    qkv_kernel<<<dim3(kN / 64, kC / 64, kB * 3), 128, 0, stream>>>(
        xT, Wqb, Wkb, Wvb, sq, bq, sk, bk, sv, bv, qT, kT, vB);
    attn_kernel<<<dim3(kN / 64, kHeads, kB * kSplit), 128, 0, stream>>>(
        qT, kT, vB, Opart, Ms, Ls);
    combine_kernel<<<dim3(kB * kN * 112 / 256), 256, 0, stream>>>(Opart, Ms, Ls, OT);
    proj_kernel<<<dim3(kN / 64, kC / 64, kB), 128, 0, stream>>>(
        OT, Wfb, bf_, sf, bff, out);
}